// Round 2
// baseline (237.088 us; speedup 1.0000x reference)
//
#include <hip/hip_runtime.h>

typedef unsigned int u32;

#define DIM 16384
#define NT  512

// XOR swizzle: inject parities of high bits into slot bits 1..3 (bit 0 preserved so
// b128 pairs {2a,2a+1} stay adjacent). Linear => swz0(y^d) = swz0(y)^swz0(d).
__host__ __device__ constexpr u32 swz0(u32 d) {
    u32 b1 = ((d >> 6) ^ (d >> 9)  ^ (d >> 12)) & 1u;
    u32 b2 = ((d >> 7) ^ (d >> 10) ^ (d >> 13)) & 1u;
    u32 b3 = ((d >> 5) ^ (d >> 8)  ^ (d >> 11)) & 1u;
    return d ^ (b1 << 1) ^ (b2 << 2) ^ (b3 << 3);
}

// CNOT-ring basis map in flat-bit space: M(y)_b = XOR_{p>=b} y_p (b<=12),
// M(y)_13 = XOR_{p<=12} y_p. GF(2)-linear. Derived from sequential CNOT(j,j+1)
// on computational basis bits (a'_j = XOR_{p<=j} a_p wires; converted to flat bits).
__host__ __device__ constexpr u32 mmap(u32 y) {
    u32 s = y;
    s ^= s >> 1; s ^= s >> 2; s ^= s >> 4; s ^= s >> 8;
    return (s & 0x1FFFu) | (((s ^ (y >> 13)) & 1u) << 13);
}

__device__ __forceinline__ void rot(float& a0, float& a1, float c, float s) {
    float n0 = fmaf(c, a0, -(s * a1));
    float n1 = fmaf(s, a0,  (c * a1));
    a0 = n0; a1 = n1;
}

// Pass <L,P>: varying bits = {0,1} + {HB..HB+2}; P==0 additionally applies the
// bit-0/bit-1 gates for the layer. P==3 performs the CNOT-ring permuted scatter
// write (L<2) or the fused measurement reduction (L==2).
template<int L, int P>
__device__ __forceinline__ void doPass(int tid, float* smem, float (&re)[32], float (&im)[32],
                                       float& acc, float W0)
{
    float2* st2 = (float2*)smem;
    const float* angC  = smem + 32768;
    const float* angS  = smem + 32768 + 48;
    const float* lutLo = smem + 32768 + 96;
    const float* lutHi = smem + 32768 + 96 + 128;

    constexpr int HB = (P == 0) ? 11 : (P == 1) ? 8 : (P == 2) ? 5 : 2;
    u32 t = (u32)tid;
    u32 ybase =
        (P == 0) ? (t << 2) :
        (P == 1) ? (((t & 63u) << 2) | ((t >> 6) << 11)) :
        (P == 2) ? (((t & 7u)  << 2) | ((t >> 3) << 8)) :
                   (t << 5);
    u32 sbase = swz0(ybase);

    if (!(L == 0 && P == 0)) {
        const float4* stv = (const float4*)st2;
        #pragma unroll
        for (int h = 0; h < 8; ++h) {
            #pragma unroll
            for (int m = 0; m < 2; ++m) {
                u32 idx = (sbase ^ swz0(((u32)h << HB) | ((u32)m << 1))) >> 1;
                float4 v = stv[idx];
                int r = h * 4 + m * 2;
                re[r] = v.x; im[r] = v.y; re[r + 1] = v.z; im[r + 1] = v.w;
            }
        }
    }

    // RY gates on bits HB..HB+2 (pairs across h)
    #pragma unroll
    for (int i = 0; i < 3; ++i) {
        float c = angC[L * 16 + HB + i];
        float s = angS[L * 16 + HB + i];
        #pragma unroll
        for (int hh = 0; hh < 8; ++hh) {
            if (hh & (1 << i)) continue;
            #pragma unroll
            for (int k = 0; k < 4; ++k) {
                int r0 = hh * 4 + k, r1 = (hh | (1 << i)) * 4 + k;
                rot(re[r0], re[r1], c, s);
                rot(im[r0], im[r1], c, s);
            }
        }
    }
    if (P == 0) {  // gates on bits 1 and 0 (wires 12, 13)
        float c1 = angC[L * 16 + 1], s1 = angS[L * 16 + 1];
        #pragma unroll
        for (int hh = 0; hh < 8; ++hh) {
            #pragma unroll
            for (int k = 0; k < 2; ++k) {
                int r0 = hh * 4 + k;
                rot(re[r0], re[r0 + 2], c1, s1);
                rot(im[r0], im[r0 + 2], c1, s1);
            }
        }
        float c0 = angC[L * 16 + 0], s0 = angS[L * 16 + 0];
        #pragma unroll
        for (int hh = 0; hh < 8; ++hh) {
            #pragma unroll
            for (int k = 0; k < 4; k += 2) {
                int r0 = hh * 4 + k;
                rot(re[r0], re[r0 + 1], c0, s0);
                rot(im[r0], im[r0 + 1], c0, s0);
            }
        }
    }

    if (P < 3) {
        float4* stv = (float4*)st2;
        #pragma unroll
        for (int h = 0; h < 8; ++h) {
            #pragma unroll
            for (int m = 0; m < 2; ++m) {
                u32 idx = (sbase ^ swz0(((u32)h << HB) | ((u32)m << 1))) >> 1;
                int r = h * 4 + m * 2;
                stv[idx] = make_float4(re[r], im[r], re[r + 1], im[r + 1]);
            }
        }
        __syncthreads();
    } else if (L < 2) {
        // permuted scatter write: new[M y] = old[y]  (b64 per amp; M splits b128 pairs).
        // RACE FIX: scatter targets other threads' read slots — all reads must
        // complete block-wide BEFORE any thread writes.
        __syncthreads();
        u32 pbase = swz0(mmap(ybase));
        #pragma unroll
        for (int h = 0; h < 8; ++h) {
            #pragma unroll
            for (int k = 0; k < 4; ++k) {
                u32 slot = pbase ^ swz0(mmap(((u32)h << 2) | (u32)k));
                int r = h * 4 + k;
                st2[slot] = make_float2(re[r], im[r]);
            }
        }
        __syncthreads();
    } else {
        // final layer: apply permutation only to the index label, reduce in-register
        u32 myb = mmap(ybase);
        #pragma unroll
        for (int h = 0; h < 8; ++h) {
            #pragma unroll
            for (int k = 0; k < 4; ++k) {
                u32 yp = myb ^ mmap(((u32)h << 2) | (u32)k);
                int r = h * 4 + k;
                float p  = fmaf(re[r], re[r], im[r] * im[r]);
                float wv = W0 - 2.0f * (lutLo[yp & 127u] + lutHi[yp >> 7]);
                acc = fmaf(wv, p, acc);
            }
        }
    }
}

__global__ __launch_bounds__(NT, 2) void qsim_kernel(
    const float* __restrict__ sreal, const float* __restrict__ simag,
    const float* __restrict__ wts,   const float* __restrict__ hw,
    const float* __restrict__ hb,    float* __restrict__ out)
{
    extern __shared__ float smem[];
    float* angC   = smem + 32768;
    float* angS   = angC + 48;
    float* lutLo  = angS + 48;
    float* lutHi  = lutLo + 128;
    float* redbuf = lutHi + 128;

    int tid = threadIdx.x;
    int b   = blockIdx.x;

    // issue state loads early (coalesced float4: lane stride 16 B)
    const float4* pr = (const float4*)(sreal + (size_t)b * DIM);
    const float4* pi = (const float4*)(simag + (size_t)b * DIM);
    float4 vr[8], vi[8];
    #pragma unroll
    for (int h = 0; h < 8; ++h) {
        vr[h] = pr[(h << 9) | tid];
        vi[h] = pi[(h << 9) | tid];
    }

    // block-uniform setup: summed half-angles (3 RYs/wire/layer compose) + head LUTs
    if (tid < 42) {
        int l = tid / 14, bb = tid % 14, q = 13 - bb;   // bit bb <-> wire 13-bb
        float a = 0.5f * (wts[l * 42 + q] + wts[l * 42 + 14 + q] + wts[l * 42 + 28 + q]);
        angC[l * 16 + bb] = cosf(a);
        angS[l * 16 + bb] = sinf(a);
    } else if (tid >= 64 && tid < 192) {
        int i = tid - 64;           // low 7 index bits -> wires 13..7
        float ssum = 0.f;
        for (int bb = 0; bb < 7; ++bb) if ((i >> bb) & 1) ssum += hw[13 - bb];
        lutLo[i] = ssum;
    } else if (tid >= 192 && tid < 320) {
        int i = tid - 192;          // high 7 index bits -> wires 6..0
        float ssum = 0.f;
        for (int bb = 0; bb < 7; ++bb) if ((i >> bb) & 1) ssum += hw[6 - bb];
        lutHi[i] = ssum;
    }

    float re[32], im[32];
    #pragma unroll
    for (int h = 0; h < 8; ++h) {
        re[h * 4 + 0] = vr[h].x; re[h * 4 + 1] = vr[h].y;
        re[h * 4 + 2] = vr[h].z; re[h * 4 + 3] = vr[h].w;
        im[h * 4 + 0] = vi[h].x; im[h * 4 + 1] = vi[h].y;
        im[h * 4 + 2] = vi[h].z; im[h * 4 + 3] = vi[h].w;
    }

    __syncthreads();
    float W0  = lutLo[127] + lutHi[127];   // sum of all head weights
    float acc = 0.f;

    doPass<0, 0>(tid, smem, re, im, acc, W0);
    doPass<0, 1>(tid, smem, re, im, acc, W0);
    doPass<0, 2>(tid, smem, re, im, acc, W0);
    doPass<0, 3>(tid, smem, re, im, acc, W0);
    doPass<1, 0>(tid, smem, re, im, acc, W0);
    doPass<1, 1>(tid, smem, re, im, acc, W0);
    doPass<1, 2>(tid, smem, re, im, acc, W0);
    doPass<1, 3>(tid, smem, re, im, acc, W0);
    doPass<2, 0>(tid, smem, re, im, acc, W0);
    doPass<2, 1>(tid, smem, re, im, acc, W0);
    doPass<2, 2>(tid, smem, re, im, acc, W0);
    doPass<2, 3>(tid, smem, re, im, acc, W0);

    // block reduction
    #pragma unroll
    for (int off = 32; off > 0; off >>= 1) acc += __shfl_xor(acc, off, 64);
    if ((tid & 63) == 0) redbuf[tid >> 6] = acc;
    __syncthreads();
    if (tid == 0) {
        float tot = hb[0];
        #pragma unroll
        for (int i = 0; i < 8; ++i) tot += redbuf[i];
        out[b] = tot;
    }
}

extern "C" void kernel_launch(void* const* d_in, const int* in_sizes, int n_in,
                              void* d_out, int out_size, void* d_ws, size_t ws_size,
                              hipStream_t stream)
{
    const float* sreal = (const float*)d_in[0];
    const float* simag = (const float*)d_in[1];
    const float* wts   = (const float*)d_in[2];
    const float* hw    = (const float*)d_in[3];
    const float* hb    = (const float*)d_in[4];
    float* out = (float*)d_out;

    int batch = in_sizes[0] / DIM;
    size_t smem_bytes = (32768 + 48 + 48 + 128 + 128 + 16) * sizeof(float);  // 132.5 KB < 160 KB

    (void)hipFuncSetAttribute((const void*)qsim_kernel,
                              hipFuncAttributeMaxDynamicSharedMemorySize, (int)smem_bytes);
    qsim_kernel<<<dim3(batch), dim3(NT), smem_bytes, stream>>>(sreal, simag, wts, hw, hb, out);
}

// Round 3
// 218.771 us; speedup vs baseline: 1.0837x; 1.0837x over previous
//
#include <hip/hip_runtime.h>

typedef unsigned int u32;

#define DIM 16384
#define NT  512

// XOR swizzle v2 (conflict model: wide LDS ops served in fixed aligned 8-lane
// phases; need (t0,t1,t2)->(idx0,idx1,idx2) invertible for every pass lane-map).
// slot1 ^= y4^y5^y8, slot2 ^= y6, slot3 ^= y7. Verified rank-3 for P0/P1/P2/P3
// lane maps and rank-4 for the mmap-scatter. Linear & involutive bijection.
__host__ __device__ constexpr u32 swz0(u32 d) {
    u32 b1 = ((d >> 4) ^ (d >> 5) ^ (d >> 8)) & 1u;
    u32 b2 = (d >> 6) & 1u;
    u32 b3 = (d >> 7) & 1u;
    return d ^ (b1 << 1) ^ (b2 << 2) ^ (b3 << 3);
}

// CNOT-ring basis map in flat-bit space: M(y)_b = XOR_{p>=b} y_p (b<=12),
// M(y)_13 = XOR_{p<=12} y_p. GF(2)-linear.
__host__ __device__ constexpr u32 mmap(u32 y) {
    u32 s = y;
    s ^= s >> 1; s ^= s >> 2; s ^= s >> 4; s ^= s >> 8;
    return (s & 0x1FFFu) | (((s ^ (y >> 13)) & 1u) << 13);
}

__device__ __forceinline__ void rot(float& a0, float& a1, float c, float s) {
    float n0 = fmaf(c, a0, -(s * a1));
    float n1 = fmaf(s, a0,  (c * a1));
    a0 = n0; a1 = n1;
}

// Pass <L,P>: varying bits = {0,1} + {HB..HB+2}; P==0 additionally applies the
// bit-0/bit-1 gates for the layer. P==3 performs the CNOT-ring permuted scatter
// write (L<2) or the fused measurement reduction (L==2).
template<int L, int P>
__device__ __forceinline__ void doPass(int tid, float* smem, float (&re)[32], float (&im)[32],
                                       float& acc, float W0)
{
    float2* st2 = (float2*)smem;
    const float* angC  = smem + 32768;
    const float* angS  = smem + 32768 + 48;
    const float* lutLo = smem + 32768 + 96;
    const float* lutHi = smem + 32768 + 96 + 128;

    constexpr int HB = (P == 0) ? 11 : (P == 1) ? 8 : (P == 2) ? 5 : 2;
    u32 t = (u32)tid;
    u32 ybase =
        (P == 0) ? (t << 2) :
        (P == 1) ? (((t & 63u) << 2) | ((t >> 6) << 11)) :
        (P == 2) ? (((t & 7u)  << 2) | ((t >> 3) << 8)) :
                   (t << 5);
    u32 sbase = swz0(ybase);

    if (!(L == 0 && P == 0)) {
        const float4* stv = (const float4*)st2;
        #pragma unroll
        for (int h = 0; h < 8; ++h) {
            #pragma unroll
            for (int m = 0; m < 2; ++m) {
                u32 idx = (sbase ^ swz0(((u32)h << HB) | ((u32)m << 1))) >> 1;
                float4 v = stv[idx];
                int r = h * 4 + m * 2;
                re[r] = v.x; im[r] = v.y; re[r + 1] = v.z; im[r + 1] = v.w;
            }
        }
    }

    // RY gates on bits HB..HB+2 (pairs across h)
    #pragma unroll
    for (int i = 0; i < 3; ++i) {
        float c = angC[L * 16 + HB + i];
        float s = angS[L * 16 + HB + i];
        #pragma unroll
        for (int hh = 0; hh < 8; ++hh) {
            if (hh & (1 << i)) continue;
            #pragma unroll
            for (int k = 0; k < 4; ++k) {
                int r0 = hh * 4 + k, r1 = (hh | (1 << i)) * 4 + k;
                rot(re[r0], re[r1], c, s);
                rot(im[r0], im[r1], c, s);
            }
        }
    }
    if (P == 0) {  // gates on bits 1 and 0 (wires 12, 13)
        float c1 = angC[L * 16 + 1], s1 = angS[L * 16 + 1];
        #pragma unroll
        for (int hh = 0; hh < 8; ++hh) {
            #pragma unroll
            for (int k = 0; k < 2; ++k) {
                int r0 = hh * 4 + k;
                rot(re[r0], re[r0 + 2], c1, s1);
                rot(im[r0], im[r0 + 2], c1, s1);
            }
        }
        float c0 = angC[L * 16 + 0], s0 = angS[L * 16 + 0];
        #pragma unroll
        for (int hh = 0; hh < 8; ++hh) {
            #pragma unroll
            for (int k = 0; k < 4; k += 2) {
                int r0 = hh * 4 + k;
                rot(re[r0], re[r0 + 1], c0, s0);
                rot(im[r0], im[r0 + 1], c0, s0);
            }
        }
    }

    if (P < 3) {
        float4* stv = (float4*)st2;
        #pragma unroll
        for (int h = 0; h < 8; ++h) {
            #pragma unroll
            for (int m = 0; m < 2; ++m) {
                u32 idx = (sbase ^ swz0(((u32)h << HB) | ((u32)m << 1))) >> 1;
                int r = h * 4 + m * 2;
                stv[idx] = make_float4(re[r], im[r], re[r + 1], im[r + 1]);
            }
        }
        __syncthreads();
    } else if (L < 2) {
        // permuted scatter write: new[M y] = old[y]  (b64 per amp; M splits b128 pairs).
        // scatter targets other threads' read slots — all reads must complete
        // block-wide BEFORE any thread writes.
        __syncthreads();
        u32 pbase = swz0(mmap(ybase));
        #pragma unroll
        for (int h = 0; h < 8; ++h) {
            #pragma unroll
            for (int k = 0; k < 4; ++k) {
                u32 slot = pbase ^ swz0(mmap(((u32)h << 2) | (u32)k));
                int r = h * 4 + k;
                st2[slot] = make_float2(re[r], im[r]);
            }
        }
        __syncthreads();
    } else {
        // final layer: apply permutation only to the index label, reduce in-register
        u32 myb = mmap(ybase);
        #pragma unroll
        for (int h = 0; h < 8; ++h) {
            #pragma unroll
            for (int k = 0; k < 4; ++k) {
                u32 yp = myb ^ mmap(((u32)h << 2) | (u32)k);
                int r = h * 4 + k;
                float p  = fmaf(re[r], re[r], im[r] * im[r]);
                float wv = W0 - 2.0f * (lutLo[yp & 127u] + lutHi[yp >> 7]);
                acc = fmaf(wv, p, acc);
            }
        }
    }
}

__global__ __launch_bounds__(NT, 2) void qsim_kernel(
    const float* __restrict__ sreal, const float* __restrict__ simag,
    const float* __restrict__ wts,   const float* __restrict__ hw,
    const float* __restrict__ hb,    float* __restrict__ out)
{
    extern __shared__ float smem[];
    float* angC   = smem + 32768;
    float* angS   = angC + 48;
    float* lutLo  = angS + 48;
    float* lutHi  = lutLo + 128;
    float* redbuf = lutHi + 128;

    int tid = threadIdx.x;
    int b   = blockIdx.x;

    // issue state loads early (coalesced float4: lane stride 16 B)
    const float4* pr = (const float4*)(sreal + (size_t)b * DIM);
    const float4* pi = (const float4*)(simag + (size_t)b * DIM);
    float4 vr[8], vi[8];
    #pragma unroll
    for (int h = 0; h < 8; ++h) {
        vr[h] = pr[(h << 9) | tid];
        vi[h] = pi[(h << 9) | tid];
    }

    // block-uniform setup: summed half-angles (3 RYs/wire/layer compose) + head LUTs
    if (tid < 42) {
        int l = tid / 14, bb = tid % 14, q = 13 - bb;   // bit bb <-> wire 13-bb
        float a = 0.5f * (wts[l * 42 + q] + wts[l * 42 + 14 + q] + wts[l * 42 + 28 + q]);
        angC[l * 16 + bb] = cosf(a);
        angS[l * 16 + bb] = sinf(a);
    } else if (tid >= 64 && tid < 192) {
        int i = tid - 64;           // low 7 index bits -> wires 13..7
        float ssum = 0.f;
        for (int bb = 0; bb < 7; ++bb) if ((i >> bb) & 1) ssum += hw[13 - bb];
        lutLo[i] = ssum;
    } else if (tid >= 192 && tid < 320) {
        int i = tid - 192;          // high 7 index bits -> wires 6..0
        float ssum = 0.f;
        for (int bb = 0; bb < 7; ++bb) if ((i >> bb) & 1) ssum += hw[6 - bb];
        lutHi[i] = ssum;
    }

    float re[32], im[32];
    #pragma unroll
    for (int h = 0; h < 8; ++h) {
        re[h * 4 + 0] = vr[h].x; re[h * 4 + 1] = vr[h].y;
        re[h * 4 + 2] = vr[h].z; re[h * 4 + 3] = vr[h].w;
        im[h * 4 + 0] = vi[h].x; im[h * 4 + 1] = vi[h].y;
        im[h * 4 + 2] = vi[h].z; im[h * 4 + 3] = vi[h].w;
    }

    __syncthreads();
    float W0  = lutLo[127] + lutHi[127];   // sum of all head weights
    float acc = 0.f;

    doPass<0, 0>(tid, smem, re, im, acc, W0);
    doPass<0, 1>(tid, smem, re, im, acc, W0);
    doPass<0, 2>(tid, smem, re, im, acc, W0);
    doPass<0, 3>(tid, smem, re, im, acc, W0);
    doPass<1, 0>(tid, smem, re, im, acc, W0);
    doPass<1, 1>(tid, smem, re, im, acc, W0);
    doPass<1, 2>(tid, smem, re, im, acc, W0);
    doPass<1, 3>(tid, smem, re, im, acc, W0);
    doPass<2, 0>(tid, smem, re, im, acc, W0);
    doPass<2, 1>(tid, smem, re, im, acc, W0);
    doPass<2, 2>(tid, smem, re, im, acc, W0);
    doPass<2, 3>(tid, smem, re, im, acc, W0);

    // block reduction
    #pragma unroll
    for (int off = 32; off > 0; off >>= 1) acc += __shfl_xor(acc, off, 64);
    if ((tid & 63) == 0) redbuf[tid >> 6] = acc;
    __syncthreads();
    if (tid == 0) {
        float tot = hb[0];
        #pragma unroll
        for (int i = 0; i < 8; ++i) tot += redbuf[i];
        out[b] = tot;
    }
}

extern "C" void kernel_launch(void* const* d_in, const int* in_sizes, int n_in,
                              void* d_out, int out_size, void* d_ws, size_t ws_size,
                              hipStream_t stream)
{
    const float* sreal = (const float*)d_in[0];
    const float* simag = (const float*)d_in[1];
    const float* wts   = (const float*)d_in[2];
    const float* hw    = (const float*)d_in[3];
    const float* hb    = (const float*)d_in[4];
    float* out = (float*)d_out;

    int batch = in_sizes[0] / DIM;
    size_t smem_bytes = (32768 + 48 + 48 + 128 + 128 + 16) * sizeof(float);  // 132.5 KB < 160 KB

    (void)hipFuncSetAttribute((const void*)qsim_kernel,
                              hipFuncAttributeMaxDynamicSharedMemorySize, (int)smem_bytes);
    qsim_kernel<<<dim3(batch), dim3(NT), smem_bytes, stream>>>(sreal, simag, wts, hw, hb, out);
}

// Round 4
// 210.499 us; speedup vs baseline: 1.1263x; 1.0393x over previous
//
#include <hip/hip_runtime.h>

typedef unsigned int u32;

#define DIM 16384
#define NT  512

// Swizzle v3: s1 = y1^y4, s2 = y2^y7, s3 = y3^y6^y8. Linear bijection (high bits
// unchanged). Rank-verified conflict-free under the 8-lane(b128)/16-lane(b64)
// phase model for: passA r/w (varying {0,1,11,12,13}), passB r/w ({6..10}),
// passC read ({0,2,3,4,5}), and the mmap-scatter (rows t0123,t0,t1,t3 = rank 4).
__host__ __device__ constexpr u32 swz0(u32 d) {
    u32 b1 = (d >> 4) & 1u;
    u32 b2 = (d >> 7) & 1u;
    u32 b3 = ((d >> 6) ^ (d >> 8)) & 1u;
    return d ^ (b1 << 1) ^ (b2 << 2) ^ (b3 << 3);
}

// CNOT-ring basis map in flat-bit space: M(y)_b = XOR_{p>=b} y_p (b<=12),
// M(y)_13 = XOR_{p<=12} y_p. GF(2)-linear. (HW-validated in R2/R3.)
__host__ __device__ constexpr u32 mmap(u32 y) {
    u32 s = y;
    s ^= s >> 1; s ^= s >> 2; s ^= s >> 4; s ^= s >> 8;
    return (s & 0x1FFFu) | (((s ^ (y >> 13)) & 1u) << 13);
}

__device__ __forceinline__ void rot(float& a0, float& a1, float c, float s) {
    float n0 = fmaf(c, a0, -(s * a1));
    float n1 = fmaf(s, a0,  (c * a1));
    a0 = n0; a1 = n1;
}

// RY on register-space bit D (partner r^D) across all 32 register amps.
template<int D>
__device__ __forceinline__ void gate32(float (&re)[32], float (&im)[32], float c, float s) {
    #pragma unroll
    for (int r = 0; r < 32; ++r) if (!(r & D)) {
        rot(re[r], re[r | D], c, s);
        rot(im[r], im[r | D], c, s);
    }
}

// Pass A: varying {0,1,11,12,13}; gates on bits 0,1,11,12,13. r = h*4+m*2+q.
// L==0 skips the LDS read (registers pre-filled from global).
template<int L>
__device__ __forceinline__ void passA(int tid, float* smem, float (&re)[32], float (&im)[32]) {
    float4* stv = (float4*)smem;
    const float* angC = smem + 32768;
    const float* angS = smem + 32768 + 48;
    u32 sbase = swz0((u32)tid << 2);
    if (L > 0) {
        #pragma unroll
        for (int h = 0; h < 8; ++h) {
            #pragma unroll
            for (int m = 0; m < 2; ++m) {
                u32 idx = (sbase ^ swz0(((u32)h << 11) | ((u32)m << 1))) >> 1;
                float4 v = stv[idx];
                int r = h * 4 + m * 2;
                re[r] = v.x; im[r] = v.y; re[r + 1] = v.z; im[r + 1] = v.w;
            }
        }
    }
    gate32<16>(re, im, angC[L * 16 + 13], angS[L * 16 + 13]);  // y13 = r bit 4
    gate32< 8>(re, im, angC[L * 16 + 12], angS[L * 16 + 12]);  // y12
    gate32< 4>(re, im, angC[L * 16 + 11], angS[L * 16 + 11]);  // y11
    gate32< 2>(re, im, angC[L * 16 +  1], angS[L * 16 +  1]);  // y1 = m
    gate32< 1>(re, im, angC[L * 16 +  0], angS[L * 16 +  0]);  // y0 = q
    #pragma unroll
    for (int h = 0; h < 8; ++h) {
        #pragma unroll
        for (int m = 0; m < 2; ++m) {
            u32 idx = (sbase ^ swz0(((u32)h << 11) | ((u32)m << 1))) >> 1;
            int r = h * 4 + m * 2;
            stv[idx] = make_float4(re[r], im[r], re[r + 1], im[r + 1]);
        }
    }
    __syncthreads();
}

// Pass B: varying {6,7,8,9,10}; gates on bits 6..10. b64 (bit 0 not varying). r = j.
template<int L>
__device__ __forceinline__ void passB(int tid, float* smem, float (&re)[32], float (&im)[32]) {
    float2* st2 = (float2*)smem;
    const float* angC = smem + 32768;
    const float* angS = smem + 32768 + 48;
    u32 ybase = ((u32)tid & 63u) | (((u32)tid >> 6) << 11);
    u32 sbase = swz0(ybase);
    #pragma unroll
    for (int j = 0; j < 32; ++j) {
        u32 slot = sbase ^ swz0((u32)j << 6);
        float2 v = st2[slot];
        re[j] = v.x; im[j] = v.y;
    }
    gate32< 1>(re, im, angC[L * 16 +  6], angS[L * 16 +  6]);
    gate32< 2>(re, im, angC[L * 16 +  7], angS[L * 16 +  7]);
    gate32< 4>(re, im, angC[L * 16 +  8], angS[L * 16 +  8]);
    gate32< 8>(re, im, angC[L * 16 +  9], angS[L * 16 +  9]);
    gate32<16>(re, im, angC[L * 16 + 10], angS[L * 16 + 10]);
    #pragma unroll
    for (int j = 0; j < 32; ++j) {
        u32 slot = sbase ^ swz0((u32)j << 6);
        st2[slot] = make_float2(re[j], im[j]);
    }
    __syncthreads();
}

// Pass C: varying {0,2,3,4,5}; gates on bits 2..5; then M-scatter (L<2) or
// fused measurement (L==2). r = h*2+q.
template<int L>
__device__ __forceinline__ void passC(int tid, float* smem, float (&re)[32], float (&im)[32],
                                      float& acc, float W0) {
    float2* st2 = (float2*)smem;
    float4* stv = (float4*)smem;
    const float* angC  = smem + 32768;
    const float* angS  = smem + 32768 + 48;
    const float* lutLo = smem + 32768 + 96;
    const float* lutHi = smem + 32768 + 96 + 128;
    u32 ybase = (((u32)tid & 1u) << 1) | (((u32)tid >> 1) << 6);
    u32 sbase = swz0(ybase);
    #pragma unroll
    for (int h = 0; h < 16; ++h) {
        u32 idx = (sbase ^ swz0((u32)h << 2)) >> 1;
        float4 v = stv[idx];
        int r = h * 2;
        re[r] = v.x; im[r] = v.y; re[r + 1] = v.z; im[r + 1] = v.w;
    }
    gate32< 2>(re, im, angC[L * 16 + 2], angS[L * 16 + 2]);  // y2 = r bit 1
    gate32< 4>(re, im, angC[L * 16 + 3], angS[L * 16 + 3]);
    gate32< 8>(re, im, angC[L * 16 + 4], angS[L * 16 + 4]);
    gate32<16>(re, im, angC[L * 16 + 5], angS[L * 16 + 5]);
    if (L < 2) {
        // scatter targets other threads' read slots: drain reads block-wide first
        __syncthreads();
        u32 pbase = swz0(mmap(ybase));
        #pragma unroll
        for (int h = 0; h < 16; ++h) {
            #pragma unroll
            for (int q = 0; q < 2; ++q) {
                u32 slot = pbase ^ swz0(mmap(((u32)h << 2) | (u32)q));
                int r = h * 2 + q;
                st2[slot] = make_float2(re[r], im[r]);
            }
        }
        __syncthreads();
    } else {
        u32 myb = mmap(ybase);
        #pragma unroll
        for (int h = 0; h < 16; ++h) {
            #pragma unroll
            for (int q = 0; q < 2; ++q) {
                u32 yp = myb ^ mmap(((u32)h << 2) | (u32)q);
                int r = h * 2 + q;
                float p  = fmaf(re[r], re[r], im[r] * im[r]);
                float wv = W0 - 2.0f * (lutLo[yp & 127u] + lutHi[yp >> 7]);
                acc = fmaf(wv, p, acc);
            }
        }
    }
}

__global__ __launch_bounds__(NT, 2) void qsim_kernel(
    const float* __restrict__ sreal, const float* __restrict__ simag,
    const float* __restrict__ wts,   const float* __restrict__ hw,
    const float* __restrict__ hb,    float* __restrict__ out)
{
    extern __shared__ float smem[];
    float* angC   = smem + 32768;
    float* angS   = angC + 48;
    float* lutLo  = angS + 48;
    float* lutHi  = lutLo + 128;
    float* redbuf = lutHi + 128;

    int tid = threadIdx.x;
    int b   = blockIdx.x;

    // global load, pass-A register layout: float4 (h<<9)|tid covers y = (h<<11)|(tid<<2)|{0..3}
    const float4* pr = (const float4*)(sreal + (size_t)b * DIM);
    const float4* pi = (const float4*)(simag + (size_t)b * DIM);
    float4 vr[8], vi[8];
    #pragma unroll
    for (int h = 0; h < 8; ++h) {
        vr[h] = pr[(h << 9) | tid];
        vi[h] = pi[(h << 9) | tid];
    }

    // block-uniform setup: summed half-angles (3 RYs/wire/layer compose) + head LUTs
    if (tid < 42) {
        int l = tid / 14, bb = tid % 14, q = 13 - bb;   // bit bb <-> wire 13-bb
        float a = 0.5f * (wts[l * 42 + q] + wts[l * 42 + 14 + q] + wts[l * 42 + 28 + q]);
        angC[l * 16 + bb] = cosf(a);
        angS[l * 16 + bb] = sinf(a);
    } else if (tid >= 64 && tid < 192) {
        int i = tid - 64;           // low 7 index bits -> wires 13..7
        float ssum = 0.f;
        for (int bb = 0; bb < 7; ++bb) if ((i >> bb) & 1) ssum += hw[13 - bb];
        lutLo[i] = ssum;
    } else if (tid >= 192 && tid < 320) {
        int i = tid - 192;          // high 7 index bits -> wires 6..0
        float ssum = 0.f;
        for (int bb = 0; bb < 7; ++bb) if ((i >> bb) & 1) ssum += hw[6 - bb];
        lutHi[i] = ssum;
    }

    float re[32], im[32];
    #pragma unroll
    for (int h = 0; h < 8; ++h) {
        re[h * 4 + 0] = vr[h].x; re[h * 4 + 1] = vr[h].y;
        re[h * 4 + 2] = vr[h].z; re[h * 4 + 3] = vr[h].w;
        im[h * 4 + 0] = vi[h].x; im[h * 4 + 1] = vi[h].y;
        im[h * 4 + 2] = vi[h].z; im[h * 4 + 3] = vi[h].w;
    }

    __syncthreads();
    float W0  = lutLo[127] + lutHi[127];   // sum of all head weights
    float acc = 0.f;

    passA<0>(tid, smem, re, im);
    passB<0>(tid, smem, re, im);
    passC<0>(tid, smem, re, im, acc, W0);
    passA<1>(tid, smem, re, im);
    passB<1>(tid, smem, re, im);
    passC<1>(tid, smem, re, im, acc, W0);
    passA<2>(tid, smem, re, im);
    passB<2>(tid, smem, re, im);
    passC<2>(tid, smem, re, im, acc, W0);

    // block reduction
    #pragma unroll
    for (int off = 32; off > 0; off >>= 1) acc += __shfl_xor(acc, off, 64);
    if ((tid & 63) == 0) redbuf[tid >> 6] = acc;
    __syncthreads();
    if (tid == 0) {
        float tot = hb[0];
        #pragma unroll
        for (int i = 0; i < 8; ++i) tot += redbuf[i];
        out[b] = tot;
    }
}

extern "C" void kernel_launch(void* const* d_in, const int* in_sizes, int n_in,
                              void* d_out, int out_size, void* d_ws, size_t ws_size,
                              hipStream_t stream)
{
    const float* sreal = (const float*)d_in[0];
    const float* simag = (const float*)d_in[1];
    const float* wts   = (const float*)d_in[2];
    const float* hw    = (const float*)d_in[3];
    const float* hb    = (const float*)d_in[4];
    float* out = (float*)d_out;

    int batch = in_sizes[0] / DIM;
    size_t smem_bytes = (32768 + 48 + 48 + 128 + 128 + 16) * sizeof(float);  // 132.5 KB < 160 KB

    (void)hipFuncSetAttribute((const void*)qsim_kernel,
                              hipFuncAttributeMaxDynamicSharedMemorySize, (int)smem_bytes);
    qsim_kernel<<<dim3(batch), dim3(NT), smem_bytes, stream>>>(sreal, simag, wts, hw, hb, out);
}

// Round 5
// 208.827 us; speedup vs baseline: 1.1353x; 1.0080x over previous
//
#include <hip/hip_runtime.h>

typedef unsigned int u32;

#define DIM 16384
#define NT  512

// Swizzle v3 (HW-validated R4): s1=y1^y4, s2=y2^y7, s3=y3^y6^y8. Conflict-free
// under the 8-lane(b128)/16-lane(b64) phase model for all pass patterns.
__host__ __device__ constexpr u32 swz0(u32 d) {
    u32 b1 = (d >> 4) & 1u;
    u32 b2 = (d >> 7) & 1u;
    u32 b3 = ((d >> 6) ^ (d >> 8)) & 1u;
    return d ^ (b1 << 1) ^ (b2 << 2) ^ (b3 << 3);
}

// CNOT-ring basis map (HW-validated R2/R3): M(y)_b = XOR_{p>=b} y_p (b<=12),
// M(y)_13 = XOR_{p<=12} y_p. GF(2)-linear.
__host__ __device__ constexpr u32 mmap(u32 y) {
    u32 s = y;
    s ^= s >> 1; s ^= s >> 2; s ^= s >> 4; s ^= s >> 8;
    return (s & 0x1FFFu) | (((s ^ (y >> 13)) & 1u) << 13);
}

// Packed rotation: amp = (re, im) in float2 -> compiler forms v_pk_mul/pk_fma
// (same scalar c,s multiplies both components: ideal VOP3P shape).
__device__ __forceinline__ void rot2(float2& a0, float2& a1, float c, float s) {
    float t0x = s * a1.x, t0y = s * a1.y;
    float t1x = s * a0.x, t1y = s * a0.y;
    float n0x = fmaf(c, a0.x, -t0x), n0y = fmaf(c, a0.y, -t0y);
    float n1x = fmaf(c, a1.x,  t1x), n1y = fmaf(c, a1.y,  t1y);
    a0.x = n0x; a0.y = n0y;
    a1.x = n1x; a1.y = n1y;
}

// RY on register-space bit D across all 32 register amps.
template<int D>
__device__ __forceinline__ void gate32(float2 (&am)[32], float c, float s) {
    #pragma unroll
    for (int r = 0; r < 32; ++r) if (!(r & D)) rot2(am[r], am[r | D], c, s);
}

// Pass A: varying {0,1,11,12,13}; gates ascending D=1,2,4,8,16 (y0,y1,y11,y12,y13)
// so gate D=1 depends only on one b128 read -> read/compute pipeline.
template<int L>
__device__ __forceinline__ void passA(int tid, float* smem, float2 (&am)[32]) {
    float4* stv = (float4*)smem;
    const float* angC = smem + 32768;
    const float* angS = smem + 32768 + 48;
    u32 sbase = swz0((u32)tid << 2);
    if (L > 0) {
        #pragma unroll
        for (int h = 0; h < 8; ++h) {
            #pragma unroll
            for (int m = 0; m < 2; ++m) {
                u32 idx = (sbase ^ swz0(((u32)h << 11) | ((u32)m << 1))) >> 1;
                float4 v = stv[idx];
                int r = h * 4 + m * 2;
                am[r]     = make_float2(v.x, v.y);
                am[r + 1] = make_float2(v.z, v.w);
            }
        }
    }
    gate32< 1>(am, angC[L * 16 +  0], angS[L * 16 +  0]);  // y0
    gate32< 2>(am, angC[L * 16 +  1], angS[L * 16 +  1]);  // y1
    gate32< 4>(am, angC[L * 16 + 11], angS[L * 16 + 11]);  // y11
    gate32< 8>(am, angC[L * 16 + 12], angS[L * 16 + 12]);  // y12
    gate32<16>(am, angC[L * 16 + 13], angS[L * 16 + 13]);  // y13
    #pragma unroll
    for (int h = 0; h < 8; ++h) {
        #pragma unroll
        for (int m = 0; m < 2; ++m) {
            u32 idx = (sbase ^ swz0(((u32)h << 11) | ((u32)m << 1))) >> 1;
            int r = h * 4 + m * 2;
            stv[idx] = make_float4(am[r].x, am[r].y, am[r + 1].x, am[r + 1].y);
        }
    }
    __syncthreads();
}

// Pass B: varying {6..10}; gates ascending (y6..y10). b64 accesses.
template<int L>
__device__ __forceinline__ void passB(int tid, float* smem, float2 (&am)[32]) {
    float2* st2 = (float2*)smem;
    const float* angC = smem + 32768;
    const float* angS = smem + 32768 + 48;
    u32 ybase = ((u32)tid & 63u) | (((u32)tid >> 6) << 11);
    u32 sbase = swz0(ybase);
    #pragma unroll
    for (int j = 0; j < 32; ++j) am[j] = st2[sbase ^ swz0((u32)j << 6)];
    gate32< 1>(am, angC[L * 16 +  6], angS[L * 16 +  6]);
    gate32< 2>(am, angC[L * 16 +  7], angS[L * 16 +  7]);
    gate32< 4>(am, angC[L * 16 +  8], angS[L * 16 +  8]);
    gate32< 8>(am, angC[L * 16 +  9], angS[L * 16 +  9]);
    gate32<16>(am, angC[L * 16 + 10], angS[L * 16 + 10]);
    #pragma unroll
    for (int j = 0; j < 32; ++j) st2[sbase ^ swz0((u32)j << 6)] = am[j];
    __syncthreads();
}

// Pass C: varying {0,2,3,4,5}; gates y2..y5 (ascending); then M-scatter (L<2)
// or fused measurement (L==2).
template<int L>
__device__ __forceinline__ void passC(int tid, float* smem, float2 (&am)[32],
                                      float& acc, float W0) {
    float2* st2 = (float2*)smem;
    float4* stv = (float4*)smem;
    const float* angC  = smem + 32768;
    const float* angS  = smem + 32768 + 48;
    const float* lutLo = smem + 32768 + 96;
    const float* lutHi = smem + 32768 + 96 + 128;
    u32 ybase = (((u32)tid & 1u) << 1) | (((u32)tid >> 1) << 6);
    u32 sbase = swz0(ybase);
    #pragma unroll
    for (int h = 0; h < 16; ++h) {
        u32 idx = (sbase ^ swz0((u32)h << 2)) >> 1;
        float4 v = stv[idx];
        int r = h * 2;
        am[r]     = make_float2(v.x, v.y);
        am[r + 1] = make_float2(v.z, v.w);
    }
    gate32< 2>(am, angC[L * 16 + 2], angS[L * 16 + 2]);  // y2
    gate32< 4>(am, angC[L * 16 + 3], angS[L * 16 + 3]);
    gate32< 8>(am, angC[L * 16 + 4], angS[L * 16 + 4]);
    gate32<16>(am, angC[L * 16 + 5], angS[L * 16 + 5]);
    if (L < 2) {
        // scatter targets other threads' read slots: drain reads block-wide first
        __syncthreads();
        u32 pbase = swz0(mmap(ybase));
        #pragma unroll
        for (int h = 0; h < 16; ++h) {
            #pragma unroll
            for (int q = 0; q < 2; ++q) {
                u32 slot = pbase ^ swz0(mmap(((u32)h << 2) | (u32)q));
                st2[slot] = am[h * 2 + q];
            }
        }
        __syncthreads();
    } else {
        u32 myb = mmap(ybase);
        #pragma unroll
        for (int h = 0; h < 16; ++h) {
            #pragma unroll
            for (int q = 0; q < 2; ++q) {
                u32 yp = myb ^ mmap(((u32)h << 2) | (u32)q);
                int r = h * 2 + q;
                float p  = fmaf(am[r].x, am[r].x, am[r].y * am[r].y);
                float wv = W0 - 2.0f * (lutLo[yp & 127u] + lutHi[yp >> 7]);
                acc = fmaf(wv, p, acc);
            }
        }
    }
}

__global__ __launch_bounds__(NT, 2) void qsim_kernel(
    const float* __restrict__ sreal, const float* __restrict__ simag,
    const float* __restrict__ wts,   const float* __restrict__ hw,
    const float* __restrict__ hb,    float* __restrict__ out)
{
    extern __shared__ float smem[];
    float* angC   = smem + 32768;
    float* angS   = angC + 48;
    float* lutLo  = angS + 48;
    float* lutHi  = lutLo + 128;
    float* redbuf = lutHi + 128;

    int tid = threadIdx.x;
    int b   = blockIdx.x;

    // global load, pass-A register layout: float4 (h<<9)|tid covers y = (h<<11)|(tid<<2)|{0..3}
    const float4* pr = (const float4*)(sreal + (size_t)b * DIM);
    const float4* pi = (const float4*)(simag + (size_t)b * DIM);
    float4 vr[8], vi[8];
    #pragma unroll
    for (int h = 0; h < 8; ++h) {
        vr[h] = pr[(h << 9) | tid];
        vi[h] = pi[(h << 9) | tid];
    }

    // block-uniform setup: summed half-angles (3 RYs/wire/layer compose) + head LUTs
    if (tid < 42) {
        int l = tid / 14, bb = tid % 14, q = 13 - bb;   // bit bb <-> wire 13-bb
        float a = 0.5f * (wts[l * 42 + q] + wts[l * 42 + 14 + q] + wts[l * 42 + 28 + q]);
        angC[l * 16 + bb] = cosf(a);
        angS[l * 16 + bb] = sinf(a);
    } else if (tid >= 64 && tid < 192) {
        int i = tid - 64;           // low 7 index bits -> wires 13..7
        float ssum = 0.f;
        for (int bb = 0; bb < 7; ++bb) if ((i >> bb) & 1) ssum += hw[13 - bb];
        lutLo[i] = ssum;
    } else if (tid >= 192 && tid < 320) {
        int i = tid - 192;          // high 7 index bits -> wires 6..0
        float ssum = 0.f;
        for (int bb = 0; bb < 7; ++bb) if ((i >> bb) & 1) ssum += hw[6 - bb];
        lutHi[i] = ssum;
    }

    float2 am[32];
    #pragma unroll
    for (int h = 0; h < 8; ++h) {
        am[h * 4 + 0] = make_float2(vr[h].x, vi[h].x);
        am[h * 4 + 1] = make_float2(vr[h].y, vi[h].y);
        am[h * 4 + 2] = make_float2(vr[h].z, vi[h].z);
        am[h * 4 + 3] = make_float2(vr[h].w, vi[h].w);
    }

    __syncthreads();
    float W0  = lutLo[127] + lutHi[127];   // sum of all head weights
    float acc = 0.f;

    passA<0>(tid, smem, am);
    passB<0>(tid, smem, am);
    passC<0>(tid, smem, am, acc, W0);
    passA<1>(tid, smem, am);
    passB<1>(tid, smem, am);
    passC<1>(tid, smem, am, acc, W0);
    passA<2>(tid, smem, am);
    passB<2>(tid, smem, am);
    passC<2>(tid, smem, am, acc, W0);

    // block reduction
    #pragma unroll
    for (int off = 32; off > 0; off >>= 1) acc += __shfl_xor(acc, off, 64);
    if ((tid & 63) == 0) redbuf[tid >> 6] = acc;
    __syncthreads();
    if (tid == 0) {
        float tot = hb[0];
        #pragma unroll
        for (int i = 0; i < 8; ++i) tot += redbuf[i];
        out[b] = tot;
    }
}

extern "C" void kernel_launch(void* const* d_in, const int* in_sizes, int n_in,
                              void* d_out, int out_size, void* d_ws, size_t ws_size,
                              hipStream_t stream)
{
    const float* sreal = (const float*)d_in[0];
    const float* simag = (const float*)d_in[1];
    const float* wts   = (const float*)d_in[2];
    const float* hw    = (const float*)d_in[3];
    const float* hb    = (const float*)d_in[4];
    float* out = (float*)d_out;

    int batch = in_sizes[0] / DIM;
    size_t smem_bytes = (32768 + 48 + 48 + 128 + 128 + 16) * sizeof(float);  // 132.5 KB < 160 KB

    (void)hipFuncSetAttribute((const void*)qsim_kernel,
                              hipFuncAttributeMaxDynamicSharedMemorySize, (int)smem_bytes);
    qsim_kernel<<<dim3(batch), dim3(NT), smem_bytes, stream>>>(sreal, simag, wts, hw, hb, out);
}